// Round 14
// baseline (711.196 us; speedup 1.0000x reference)
//
#include <hip/hip_runtime.h>

typedef __attribute__((ext_vector_type(8))) _Float16 f16x8;
typedef __attribute__((ext_vector_type(4))) _Float16 f16x4;
typedef __attribute__((ext_vector_type(4))) float f32x4;

#define PWS 72   // LDS tile pitch in halfs: 144B rows, 16B-aligned chunks

__device__ __forceinline__ float silu_f(float v) {
    return v * (1.0f / (1.0f + __expf(-v)));
}

// bijective XCD-aware block swizzle (identity for tiny grids)
__device__ __forceinline__ int xcd_swz(int bid, int nwg) {
    if (nwg < 16) return bid;
    int q = nwg >> 3, r = nwg & 7;
    int x = bid & 7, i = bid >> 3;
    int basex = (x < r) ? x * (q + 1) : r * (q + 1) + (x - r) * q;
    return basex + i;
}

// ---------------------------------------------------------------------------
// Weight pre-conversion: fp32 [K][64] -> f16 in B-fragment order.
// ---------------------------------------------------------------------------
struct WDesc { const float* W; _Float16* out; int K; };
struct WPack { WDesc d[8]; };

__global__ __launch_bounds__(256) void conv_weights(WPack p) {
    WDesc wd = p.d[blockIdx.y];
    int total = wd.K * 64;
    int i = blockIdx.x * 256 + threadIdx.x;
    if (i >= total) return;
    int j  = i & 7;
    int l  = (i >> 3) & 63;
    int tn = i >> 9;                 // t*4 + nf
    int t  = tn >> 2, nf = tn & 3;
    int k  = t * 32 + (l >> 4) * 8 + j;
    int c  = nf * 16 + (l & 15);
    wd.out[i] = (_Float16)wd.W[k * 64 + c];   // RNE
}

// ---------------------------------------------------------------------------
// CSR build: histogram -> single-block scan -> scatter (packed int4 records).
// ---------------------------------------------------------------------------
__global__ __launch_bounds__(256) void hist_kernel(const int* __restrict__ dst,
                                                   int* __restrict__ counts, int E) {
    int e = blockIdx.x * 256 + threadIdx.x;
    if (e < E) atomicAdd(&counts[dst[e]], 1);
}

__global__ __launch_bounds__(1024) void scan_kernel(int* __restrict__ counts,
                                                    int* __restrict__ row_ptr,
                                                    int N, int E) {
    __shared__ int part[1024];
    int t = threadIdx.x;
    int per = (N + 1023) >> 10;
    int s = t * per, en = min(s + per, N);
    int sum = 0;
    for (int i = s; i < en; ++i) sum += counts[i];
    part[t] = sum;
    __syncthreads();
    for (int off = 1; off < 1024; off <<= 1) {
        int v = (t >= off) ? part[t - off] : 0;
        __syncthreads();
        part[t] += v;
        __syncthreads();
    }
    int run = (t == 0) ? 0 : part[t - 1];
    for (int i = s; i < en; ++i) {
        int c = counts[i];
        row_ptr[i] = run;
        counts[i] = run;        // becomes the scatter cursor
        run += c;
    }
    if (t == 1023) row_ptr[N] = E;
}

__global__ __launch_bounds__(256) void scatter_kernel(
    const int* __restrict__ src, const int* __restrict__ dst,
    int* __restrict__ cursor, int4* __restrict__ pk, int E) {
    int e = blockIdx.x * 256 + threadIdx.x;
    if (e < E) {
        int d = dst[e];
        int pos = atomicAdd(&cursor[d], 1);
        pk[pos] = make_int4(e, src[e], d, 0);   // one 16B record
    }
}

// ---------------------------------------------------------------------------
// Sorted edge kernel with FUSED run-compressed atomic aggregation.
// 4 independent waves/block, wave owns 16 dst-sorted positions. Epilogue:
// consecutive rows sharing a dst are pre-summed in registers; one atomicAdd
// row per run boundary (~4.8 rows/wave vs 16 unsorted; time-sorted -> L2
// locality). ea_mid f16 written sequentially; FINAL also scatters fp32
// ea_out[eid].
// ---------------------------------------------------------------------------
template <bool IN16, bool FINAL>
__global__ __launch_bounds__(256, 8) void gnn_edge_sorted(
    const float* __restrict__ x,
    const float* __restrict__ ea0,
    _Float16* __restrict__ ea_mid,
    float* __restrict__ ea_out,
    const int4* __restrict__ pk,
    const _Float16* __restrict__ w1f,
    const float* __restrict__ b1,
    const _Float16* __restrict__ w2f,
    const float* __restrict__ b2,
    float* __restrict__ agg,
    int E, int nwg)
{
    __shared__ __align__(16) _Float16 sA[64][PWS];

    const int t    = threadIdx.x;
    const int lane = t & 63;
    const int w    = t >> 6;
    const int col  = lane & 15;
    const int g    = lane >> 4;
    const int ko   = g * 8;
    const int bid  = xcd_swz(blockIdx.x, nwg);
    const long base = (long)bid * 64;

    // this lane's own position record (eid + dst for the shfl'd epilogue)
    long p0 = base + w * 16 + col;
    if (p0 >= E) p0 = E - 1;
    const int4 rec0 = pk[p0];
    const int ei0 = rec0.x;
    const int d0  = rec0.z;

    // ---- upfront loads: rows it*4+g of the wave tile, cols col*4..+4 ----
    f16x4  ea16v[4];
    float4 ea4[4];
    float4 sx4[4], dx4[4];
#pragma unroll
    for (int it = 0; it < 4; ++it) {
        long p = base + w * 16 + it * 4 + g;
        if (p >= E) p = E - 1;
        int4 rec = pk[p];
        if constexpr (IN16) {
            ea16v[it] = *(const f16x4*)(ea_mid + p * 64 + col * 4);
        } else {
            ea4[it] = *(const float4*)(ea0 + (long)rec.x * 64 + col * 4);
        }
        sx4[it] = *(const float4*)(x + (long)rec.y * 64 + col * 4);
        dx4[it] = *(const float4*)(x + (long)rec.z * 64 + col * 4);
    }

    f32x4 acc[4];
#pragma unroll
    for (int nf = 0; nf < 4; ++nf) {
        float bv = b1[nf * 16 + col];
        acc[nf] = (f32x4){bv, bv, bv, bv};
    }

    const int arow = w * 16 + col;

#define MFMA_L1(s3)                                                             \
    _Pragma("unroll")                                                           \
    for (int tt = 0; tt < 2; ++tt) {                                            \
        int k0 = tt * 32 + ko;                                                  \
        f16x8 af = *(const f16x8*)&sA[arow][k0];                                \
        int tg = (s3) * 2 + tt;                                                 \
        _Pragma("unroll")                                                       \
        for (int nf = 0; nf < 4; ++nf) {                                        \
            f16x8 bf = *(const f16x8*)(w1f + (size_t)((tg*4+nf)*64+lane)*8);    \
            acc[nf] = __builtin_amdgcn_mfma_f32_16x16x32_f16(af, bf, acc[nf], 0, 0, 0); \
        }                                                                       \
    }

    // ---- segment 0: edge_attr (k 0..63) ----
#pragma unroll
    for (int it = 0; it < 4; ++it) {
        int rg = w * 16 + it * 4 + g;
        f16x4 hv;
        if constexpr (IN16) {
            hv = ea16v[it];
        } else {
            hv[0] = (_Float16)ea4[it].x; hv[1] = (_Float16)ea4[it].y;
            hv[2] = (_Float16)ea4[it].z; hv[3] = (_Float16)ea4[it].w;
        }
        *(f16x4*)&sA[rg][col * 4] = hv;
    }
    MFMA_L1(0)

    // ---- segment 1: x[src] (k 64..127) ----
#pragma unroll
    for (int it = 0; it < 4; ++it) {
        int rg = w * 16 + it * 4 + g;
        f16x4 hv;
        hv[0] = (_Float16)sx4[it].x; hv[1] = (_Float16)sx4[it].y;
        hv[2] = (_Float16)sx4[it].z; hv[3] = (_Float16)sx4[it].w;
        *(f16x4*)&sA[rg][col * 4] = hv;
    }
    MFMA_L1(1)

    // ---- segment 2: x[dst] (k 128..191) ----
#pragma unroll
    for (int it = 0; it < 4; ++it) {
        int rg = w * 16 + it * 4 + g;
        f16x4 hv;
        hv[0] = (_Float16)dx4[it].x; hv[1] = (_Float16)dx4[it].y;
        hv[2] = (_Float16)dx4[it].z; hv[3] = (_Float16)dx4[it].w;
        *(f16x4*)&sA[rg][col * 4] = hv;
    }
    MFMA_L1(2)
#undef MFMA_L1

    // ---- silu -> h staged into the wave's own 16 LDS rows (C-frag layout) ----
#pragma unroll
    for (int nf = 0; nf < 4; ++nf)
#pragma unroll
        for (int rg = 0; rg < 4; ++rg) {
            int row = w * 16 + g * 4 + rg;
            sA[row][nf * 16 + col] = (_Float16)silu_f(acc[nf][rg]);
        }

    // ---- layer-2 GEMM (K=64) ----
    f32x4 out[4];
#pragma unroll
    for (int nf = 0; nf < 4; ++nf) {
        float bv = b2[nf * 16 + col];
        out[nf] = (f32x4){bv, bv, bv, bv};
    }
#pragma unroll
    for (int tt = 0; tt < 2; ++tt) {
        int k0 = tt * 32 + ko;
        f16x8 af = *(const f16x8*)&sA[arow][k0];
#pragma unroll
        for (int nf = 0; nf < 4; ++nf) {
            f16x8 bf = *(const f16x8*)(w2f + (size_t)((tt * 4 + nf) * 64 + lane) * 8);
            out[nf] = __builtin_amdgcn_mfma_f32_16x16x32_f16(af, bf, out[nf], 0, 0, 0);
        }
    }

    // ---- epilogue: ea_mid write + run-compressed atomic scatter (+FINAL) ----
    const int rbase = w * 16 + g * 4;
    int dcur = -1;
    float r0 = 0.f, r1 = 0.f, r2 = 0.f, r3 = 0.f;
#pragma unroll
    for (int rg = 0; rg < 4; ++rg) {
        long p = base + rbase + rg;
        int dn = __shfl(d0, g * 4 + rg);   // lane col==g*4+rg holds this row's dst
        if (p < E) {
#pragma unroll
            for (int nf = 0; nf < 4; ++nf)
                ea_mid[p * 64 + nf * 16 + col] = (_Float16)out[nf][rg];
            if constexpr (FINAL) {
                int eid = __shfl(ei0, g * 4 + rg);
                float* op = ea_out + (long)eid * 64;
#pragma unroll
                for (int nf = 0; nf < 4; ++nf)
                    op[nf * 16 + col] = out[nf][rg];
            }
            if (dn != dcur) {
                if (dcur >= 0) {
                    float* ap = agg + (long)dcur * 64;
                    atomicAdd(&ap[col],      r0);
                    atomicAdd(&ap[16 + col], r1);
                    atomicAdd(&ap[32 + col], r2);
                    atomicAdd(&ap[48 + col], r3);
                }
                dcur = dn; r0 = r1 = r2 = r3 = 0.f;
            }
            r0 += out[0][rg]; r1 += out[1][rg];
            r2 += out[2][rg]; r3 += out[3][rg];
        }
    }
    if (dcur >= 0) {
        float* ap = agg + (long)dcur * 64;
        atomicAdd(&ap[col],      r0);
        atomicAdd(&ap[16 + col], r1);
        atomicAdd(&ap[32 + col], r2);
        atomicAdd(&ap[48 + col], r3);
    }
}

// ---------------------------------------------------------------------------
// Node kernel: direct A-fragment loads (x, agg rows sequential), LDS only for
// the h transpose. No atomics.
// ---------------------------------------------------------------------------
__global__ __launch_bounds__(256, 8) void gnn_node_mfma(
    const float* __restrict__ x_in,
    const float* __restrict__ aggp,
    float* __restrict__ x_out,
    const _Float16* __restrict__ w1f,
    const float* __restrict__ b1,
    const _Float16* __restrict__ w2f,
    const float* __restrict__ b2, int N)
{
    __shared__ __align__(16) _Float16 sA[64][PWS];

    const int t    = threadIdx.x;
    const int lane = t & 63;
    const int w    = t >> 6;
    const int col  = lane & 15;
    const int g    = lane >> 4;
    const int ko   = g * 8;
    const long base = (long)blockIdx.x * 64;

    long nr = base + w * 16 + col;
    if (nr >= N) nr = N - 1;
    const float* px = x_in + nr * 64 + ko;
    const float* pa = aggp + nr * 64 + ko;

    float4 v0 = *(const float4*)(px);
    float4 v1 = *(const float4*)(px + 4);
    float4 v2 = *(const float4*)(px + 32);
    float4 v3 = *(const float4*)(px + 36);
    float4 v4 = *(const float4*)(pa);
    float4 v5 = *(const float4*)(pa + 4);
    float4 v6 = *(const float4*)(pa + 32);
    float4 v7 = *(const float4*)(pa + 36);

    f32x4 acc[4];
#pragma unroll
    for (int nf = 0; nf < 4; ++nf) {
        float bv = b1[nf * 16 + col];
        acc[nf] = (f32x4){bv, bv, bv, bv};
    }

#define QTR(m, A, B)                                                            \
    {                                                                           \
        f16x8 af;                                                               \
        af[0] = (_Float16)A.x; af[1] = (_Float16)A.y;                           \
        af[2] = (_Float16)A.z; af[3] = (_Float16)A.w;                           \
        af[4] = (_Float16)B.x; af[5] = (_Float16)B.y;                           \
        af[6] = (_Float16)B.z; af[7] = (_Float16)B.w;                           \
        _Pragma("unroll")                                                       \
        for (int nf = 0; nf < 4; ++nf) {                                        \
            f16x8 bf = *(const f16x8*)(w1f + (size_t)(((m)*4+nf)*64+lane)*8);   \
            acc[nf] = __builtin_amdgcn_mfma_f32_16x16x32_f16(af, bf, acc[nf], 0, 0, 0); \
        }                                                                       \
    }
    QTR(0, v0, v1)  QTR(1, v2, v3)   // x    (k 0..63)
    QTR(2, v4, v5)  QTR(3, v6, v7)   // agg  (k 64..127)
#undef QTR

#pragma unroll
    for (int nf = 0; nf < 4; ++nf)
#pragma unroll
        for (int rg = 0; rg < 4; ++rg) {
            int row = w * 16 + g * 4 + rg;
            sA[row][nf * 16 + col] = (_Float16)silu_f(acc[nf][rg]);
        }

    f32x4 out[4];
#pragma unroll
    for (int nf = 0; nf < 4; ++nf) {
        float bv = b2[nf * 16 + col];
        out[nf] = (f32x4){bv, bv, bv, bv};
    }
    const int arow = w * 16 + col;
#pragma unroll
    for (int tt = 0; tt < 2; ++tt) {
        int k0 = tt * 32 + ko;
        f16x8 af = *(const f16x8*)&sA[arow][k0];
#pragma unroll
        for (int nf = 0; nf < 4; ++nf) {
            f16x8 bf = *(const f16x8*)(w2f + (size_t)((tt * 4 + nf) * 64 + lane) * 8);
            out[nf] = __builtin_amdgcn_mfma_f32_16x16x32_f16(af, bf, out[nf], 0, 0, 0);
        }
    }

    const int rbase = w * 16 + g * 4;
#pragma unroll
    for (int rg = 0; rg < 4; ++rg) {
        long row = base + rbase + rg;
        if (row < N) {
            float* op = x_out + row * 64;
#pragma unroll
            for (int nf = 0; nf < 4; ++nf)
                op[nf * 16 + col] = out[nf][rg];
        }
    }
}

// ---------------------------------------------------------------------------
// Fallback unsorted edge kernel (atomics) — used only if workspace too small.
// ---------------------------------------------------------------------------
__global__ __launch_bounds__(256, 8) void gnn_edge_mfma(
    const float* __restrict__ x,
    const float* __restrict__ ea_in,
    float* __restrict__ ea_out,
    const int* __restrict__ src_idx,
    const int* __restrict__ dst_idx,
    const _Float16* __restrict__ w1f,
    const float* __restrict__ b1,
    const _Float16* __restrict__ w2f,
    const float* __restrict__ b2,
    float* __restrict__ agg,
    int E)
{
    __shared__ __align__(16) _Float16 sA[64][PWS];

    const int t    = threadIdx.x;
    const int lane = t & 63;
    const int w    = t >> 6;
    const int col  = lane & 15;
    const int g    = lane >> 4;
    const int ko   = g * 8;
    const long base = (long)blockIdx.x * 64;

    long er0 = base + w * 16 + col;
    if (er0 >= E) er0 = E - 1;
    const int di = dst_idx[er0];

    float4 ea4[4], sx4[4], dx4[4];
#pragma unroll
    for (int it = 0; it < 4; ++it) {
        long er = base + w * 16 + it * 4 + g;
        if (er >= E) er = E - 1;
        ea4[it] = *(const float4*)(ea_in + er * 64 + col * 4);
        sx4[it] = *(const float4*)(x + (long)src_idx[er] * 64 + col * 4);
        dx4[it] = *(const float4*)(x + (long)dst_idx[er] * 64 + col * 4);
    }

    f32x4 acc[4];
#pragma unroll
    for (int nf = 0; nf < 4; ++nf) {
        float bv = b1[nf * 16 + col];
        acc[nf] = (f32x4){bv, bv, bv, bv};
    }
    const int arow = w * 16 + col;

#define MFMA_L1(s3)                                                             \
    _Pragma("unroll")                                                           \
    for (int tt = 0; tt < 2; ++tt) {                                            \
        int k0 = tt * 32 + ko;                                                  \
        f16x8 af = *(const f16x8*)&sA[arow][k0];                                \
        int tg = (s3) * 2 + tt;                                                 \
        _Pragma("unroll")                                                       \
        for (int nf = 0; nf < 4; ++nf) {                                        \
            f16x8 bf = *(const f16x8*)(w1f + (size_t)((tg*4+nf)*64+lane)*8);    \
            acc[nf] = __builtin_amdgcn_mfma_f32_16x16x32_f16(af, bf, acc[nf], 0, 0, 0); \
        }                                                                       \
    }

#pragma unroll
    for (int it = 0; it < 4; ++it) {
        int rg = w * 16 + it * 4 + g;
        f16x4 hv;
        hv[0] = (_Float16)ea4[it].x; hv[1] = (_Float16)ea4[it].y;
        hv[2] = (_Float16)ea4[it].z; hv[3] = (_Float16)ea4[it].w;
        *(f16x4*)&sA[rg][col * 4] = hv;
    }
    MFMA_L1(0)
#pragma unroll
    for (int it = 0; it < 4; ++it) {
        int rg = w * 16 + it * 4 + g;
        f16x4 hv;
        hv[0] = (_Float16)sx4[it].x; hv[1] = (_Float16)sx4[it].y;
        hv[2] = (_Float16)sx4[it].z; hv[3] = (_Float16)sx4[it].w;
        *(f16x4*)&sA[rg][col * 4] = hv;
    }
    MFMA_L1(1)
#pragma unroll
    for (int it = 0; it < 4; ++it) {
        int rg = w * 16 + it * 4 + g;
        f16x4 hv;
        hv[0] = (_Float16)dx4[it].x; hv[1] = (_Float16)dx4[it].y;
        hv[2] = (_Float16)dx4[it].z; hv[3] = (_Float16)dx4[it].w;
        *(f16x4*)&sA[rg][col * 4] = hv;
    }
    MFMA_L1(2)
#undef MFMA_L1

#pragma unroll
    for (int nf = 0; nf < 4; ++nf)
#pragma unroll
        for (int rg = 0; rg < 4; ++rg) {
            int row = w * 16 + g * 4 + rg;
            sA[row][nf * 16 + col] = (_Float16)silu_f(acc[nf][rg]);
        }

    f32x4 out[4];
#pragma unroll
    for (int nf = 0; nf < 4; ++nf) {
        float bv = b2[nf * 16 + col];
        out[nf] = (f32x4){bv, bv, bv, bv};
    }
#pragma unroll
    for (int tt = 0; tt < 2; ++tt) {
        int k0 = tt * 32 + ko;
        f16x8 af = *(const f16x8*)&sA[arow][k0];
#pragma unroll
        for (int nf = 0; nf < 4; ++nf) {
            f16x8 bf = *(const f16x8*)(w2f + (size_t)((tt * 4 + nf) * 64 + lane) * 8);
            out[nf] = __builtin_amdgcn_mfma_f32_16x16x32_f16(af, bf, out[nf], 0, 0, 0);
        }
    }

    const int rbase = w * 16 + g * 4;
#pragma unroll
    for (int rg = 0; rg < 4; ++rg) {
        long row = base + rbase + rg;
        if (row < E) {
            int drow = __shfl(di, g * 4 + rg);
            float* ap = agg + (long)drow * 64;
#pragma unroll
            for (int nf = 0; nf < 4; ++nf) {
                ea_out[row * 64 + nf * 16 + col] = out[nf][rg];
                atomicAdd(&ap[nf * 16 + col], out[nf][rg]);
            }
        }
    }
}

extern "C" void kernel_launch(void* const* d_in, const int* in_sizes, int n_in,
                              void* d_out, int out_size, void* d_ws, size_t ws_size,
                              hipStream_t stream) {
    const int H = 64;
    const int N = in_sizes[0] / H;   // 50000
    const int E = in_sizes[1] / H;   // 800000

    const float* x0  = (const float*)d_in[0];
    const float* ea0 = (const float*)d_in[1];
    const int*   ei  = (const int*)d_in[2];
    const float* ew1 = (const float*)d_in[3];
    const float* eb1 = (const float*)d_in[4];
    const float* ew2 = (const float*)d_in[5];
    const float* eb2 = (const float*)d_in[6];
    const float* nw1 = (const float*)d_in[7];
    const float* nb1 = (const float*)d_in[8];
    const float* nw2 = (const float*)d_in[9];
    const float* nb2 = (const float*)d_in[10];

    float* outX = (float*)d_out;                 // [N, H]
    float* outE = outX + (size_t)N * H;          // [E, H]

    // workspace carve: agg | weights | eaH f16 | counts | row_ptr | pk
    const size_t aggBytes = (size_t)N * H * sizeof(float);
    const size_t wElems   = 2 * ((size_t)(192 + 64 + 128 + 64) * 64);
    const size_t eaHBytes = (size_t)E * H * sizeof(_Float16);

    float* agg      = (float*)d_ws;
    _Float16* wbase = (_Float16*)((char*)d_ws + aggBytes);
    char* eaH_raw   = (char*)(wbase + wElems);
    eaH_raw = (char*)(((uintptr_t)eaH_raw + 15) & ~(uintptr_t)15);
    _Float16* eaH   = (_Float16*)eaH_raw;
    int* counts     = (int*)(((uintptr_t)((char*)eaH + eaHBytes) + 15) & ~(uintptr_t)15);
    int* row_ptr    = counts + N;
    int4* pk        = (int4*)(((uintptr_t)(row_ptr + N + 1) + 15) & ~(uintptr_t)15);

    const bool sortedOK = ((char*)(pk + E)) <= ((char*)d_ws + ws_size);

    const int* srcI = ei;
    const int* dstI = ei + E;

    WPack pack;
    size_t off = 0;
    _Float16* EW1[2]; _Float16* EW2[2]; _Float16* NW1[2]; _Float16* NW2[2];
    for (int l = 0; l < 2; ++l) {
        EW1[l] = wbase + off; off += 192 * 64;
        EW2[l] = wbase + off; off += 64 * 64;
        NW1[l] = wbase + off; off += 128 * 64;
        NW2[l] = wbase + off; off += 64 * 64;
        pack.d[l * 4 + 0] = {ew1 + (size_t)l * 192 * 64, EW1[l], 192};
        pack.d[l * 4 + 1] = {ew2 + (size_t)l * 64 * 64,  EW2[l], 64};
        pack.d[l * 4 + 2] = {nw1 + (size_t)l * 128 * 64, NW1[l], 128};
        pack.d[l * 4 + 3] = {nw2 + (size_t)l * 64 * 64,  NW2[l], 64};
    }
    conv_weights<<<dim3(48, 8), 256, 0, stream>>>(pack);

    const int egrid = (E + 63) / 64;
    const int ngrid = (N + 63) / 64;

    if (sortedOK) {
        // ---- CSR build (once) ----
        (void)hipMemsetAsync(counts, 0, (size_t)N * sizeof(int), stream);
        hist_kernel<<<(E + 255) / 256, 256, 0, stream>>>(dstI, counts, E);
        scan_kernel<<<1, 1024, 0, stream>>>(counts, row_ptr, N, E);
        scatter_kernel<<<(E + 255) / 256, 256, 0, stream>>>(
            srcI, dstI, counts, pk, E);

        // layer 1
        (void)hipMemsetAsync(agg, 0, aggBytes, stream);
        gnn_edge_sorted<false, false><<<egrid, 256, 0, stream>>>(
            x0, ea0, eaH, nullptr, pk,
            EW1[0], eb1, EW2[0], eb2, agg, E, egrid);
        gnn_node_mfma<<<ngrid, 256, 0, stream>>>(
            x0, agg, outX, NW1[0], nb1, NW2[0], nb2, N);

        // layer 2 (ea_mid in-place + final outE scatter)
        (void)hipMemsetAsync(agg, 0, aggBytes, stream);
        gnn_edge_sorted<true, true><<<egrid, 256, 0, stream>>>(
            outX, nullptr, eaH, outE, pk,
            EW1[1], eb1 + H, EW2[1], eb2 + H, agg, E, egrid);
        gnn_node_mfma<<<ngrid, 256, 0, stream>>>(
            outX, agg, outX, NW1[1], nb1 + H, NW2[1], nb2 + H, N);
    } else {
        // fallback: unsorted path with atomics
        for (int l = 0; l < 2; ++l) {
            const float* xin  = (l == 0) ? x0  : outX;
            const float* eain = (l == 0) ? ea0 : outE;
            (void)hipMemsetAsync(agg, 0, aggBytes, stream);
            gnn_edge_mfma<<<egrid, 256, 0, stream>>>(
                xin, eain, outE, srcI, dstI,
                EW1[l], eb1 + l * H, EW2[l], eb2 + l * H, agg, E);
            gnn_node_mfma<<<ngrid, 256, 0, stream>>>(
                xin, agg, outX,
                NW1[l], nb1 + l * H, NW2[l], nb2 + l * H, N);
        }
    }
}

// Round 15
// 472.227 us; speedup vs baseline: 1.5060x; 1.5060x over previous
//
#include <hip/hip_runtime.h>

typedef __attribute__((ext_vector_type(8))) _Float16 f16x8;
typedef __attribute__((ext_vector_type(4))) _Float16 f16x4;
typedef __attribute__((ext_vector_type(4))) float f32x4;

#define PWS 72   // LDS tile pitch in halfs: 144B rows, 16B-aligned chunks

__device__ __forceinline__ float silu_f(float v) {
    return v * (1.0f / (1.0f + __expf(-v)));
}

// bijective XCD-aware block swizzle (identity for tiny grids)
__device__ __forceinline__ int xcd_swz(int bid, int nwg) {
    if (nwg < 16) return bid;
    int q = nwg >> 3, r = nwg & 7;
    int x = bid & 7, i = bid >> 3;
    int basex = (x < r) ? x * (q + 1) : r * (q + 1) + (x - r) * q;
    return basex + i;
}

// ---------------------------------------------------------------------------
// Weight pre-conversion: fp32 [K][64] -> f16 in B-fragment order.
// ---------------------------------------------------------------------------
struct WDesc { const float* W; _Float16* out; int K; };
struct WPack { WDesc d[8]; };

__global__ __launch_bounds__(256) void conv_weights(WPack p) {
    WDesc wd = p.d[blockIdx.y];
    int total = wd.K * 64;
    int i = blockIdx.x * 256 + threadIdx.x;
    if (i >= total) return;
    int j  = i & 7;
    int l  = (i >> 3) & 63;
    int tn = i >> 9;                 // t*4 + nf
    int t  = tn >> 2, nf = tn & 3;
    int k  = t * 32 + (l >> 4) * 8 + j;
    int c  = nf * 16 + (l & 15);
    wd.out[i] = (_Float16)wd.W[k * 64 + c];   // RNE
}

// ---------------------------------------------------------------------------
// CSR build: histogram -> parallel 3-phase scan -> scatter (pk + pos arrays).
// ---------------------------------------------------------------------------
__global__ __launch_bounds__(256) void hist_kernel(const int* __restrict__ dst,
                                                   int* __restrict__ counts, int E) {
    int e = blockIdx.x * 256 + threadIdx.x;
    if (e < E) atomicAdd(&counts[dst[e]], 1);
}

__global__ __launch_bounds__(256) void scan_part(const int* __restrict__ counts,
                                                 int* __restrict__ partial, int N) {
    __shared__ int sm[256];
    int t = threadIdx.x;
    int i = blockIdx.x * 256 + t;
    sm[t] = (i < N) ? counts[i] : 0;
    __syncthreads();
    for (int off = 128; off > 0; off >>= 1) {
        if (t < off) sm[t] += sm[t + off];
        __syncthreads();
    }
    if (t == 0) partial[blockIdx.x] = sm[0];
}

__global__ __launch_bounds__(256) void scan_mid(int* __restrict__ partial, int nP) {
    __shared__ int sm[256];
    int t = threadIdx.x;
    int v = (t < nP) ? partial[t] : 0;
    sm[t] = v;
    __syncthreads();
    for (int off = 1; off < 256; off <<= 1) {
        int add = (t >= off) ? sm[t - off] : 0;
        __syncthreads();
        sm[t] += add;
        __syncthreads();
    }
    if (t < nP) partial[t] = sm[t] - v;      // exclusive base per block
}

__global__ __launch_bounds__(256) void scan_fin(int* __restrict__ counts,
                                                const int* __restrict__ partial,
                                                int* __restrict__ row_ptr,
                                                int N, int E) {
    __shared__ int sm[256];
    int t = threadIdx.x;
    int i = blockIdx.x * 256 + t;
    int v = (i < N) ? counts[i] : 0;
    sm[t] = v;
    __syncthreads();
    for (int off = 1; off < 256; off <<= 1) {
        int add = (t >= off) ? sm[t - off] : 0;
        __syncthreads();
        sm[t] += add;
        __syncthreads();
    }
    int excl = sm[t] - v + partial[blockIdx.x];
    if (i < N) { row_ptr[i] = excl; counts[i] = excl; }   // counts becomes cursor
    if (blockIdx.x == 0 && t == 0) row_ptr[N] = E;
}

__global__ __launch_bounds__(256) void scatter_kernel(
    const int* __restrict__ src, const int* __restrict__ dst,
    int* __restrict__ cursor, int4* __restrict__ pk,
    int* __restrict__ posA, int E) {
    int e = blockIdx.x * 256 + threadIdx.x;
    if (e < E) {
        int d = dst[e];
        int pos = atomicAdd(&cursor[d], 1);
        pk[pos] = make_int4(e, src[e], d, 0);
        posA[e] = pos;
    }
}

// ---------------------------------------------------------------------------
// Layer-1 edge kernel, ORIGINAL edge order: sequential ea0 fp32 read, x
// gathers (x is L2/L3-resident), no atomics. Result scatter-written as f16
// into sorted ea_mid[pos[e]] (the only scattered traffic, 102 MB).
// 4 independent waves/block, wave owns 16 edges, no barriers.
// ---------------------------------------------------------------------------
__global__ __launch_bounds__(256, 8) void gnn_edge_l1(
    const float* __restrict__ x,
    const float* __restrict__ ea_in,
    _Float16* __restrict__ ea_mid,
    const int* __restrict__ src_idx,
    const int* __restrict__ dst_idx,
    const int* __restrict__ posA,
    const _Float16* __restrict__ w1f, const float* __restrict__ b1,
    const _Float16* __restrict__ w2f, const float* __restrict__ b2,
    int E, int nwg)
{
    __shared__ __align__(16) _Float16 sA[64][PWS];

    const int t    = threadIdx.x;
    const int lane = t & 63;
    const int w    = t >> 6;
    const int col  = lane & 15;
    const int g    = lane >> 4;
    const int ko   = g * 8;
    const int bid  = xcd_swz(blockIdx.x, nwg);
    const long base = (long)bid * 64;

    long er0 = base + w * 16 + col;
    if (er0 >= E) er0 = E - 1;
    const int p0 = posA[er0];          // sorted position of this lane's row

    // ---- upfront loads: rows it*4+g, cols col*4..+4; ea sequential ----
    float4 ea4[4], sx4[4], dx4[4];
#pragma unroll
    for (int it = 0; it < 4; ++it) {
        long er = base + w * 16 + it * 4 + g;
        if (er >= E) er = E - 1;
        ea4[it] = *(const float4*)(ea_in + er * 64 + col * 4);
        sx4[it] = *(const float4*)(x + (long)src_idx[er] * 64 + col * 4);
        dx4[it] = *(const float4*)(x + (long)dst_idx[er] * 64 + col * 4);
    }

    f32x4 acc[4];
#pragma unroll
    for (int nf = 0; nf < 4; ++nf) {
        float bv = b1[nf * 16 + col];
        acc[nf] = (f32x4){bv, bv, bv, bv};
    }
    const int arow = w * 16 + col;

#define MFMA_L1(s3)                                                             \
    _Pragma("unroll")                                                           \
    for (int tt = 0; tt < 2; ++tt) {                                            \
        int k0 = tt * 32 + ko;                                                  \
        f16x8 af = *(const f16x8*)&sA[arow][k0];                                \
        int tg = (s3) * 2 + tt;                                                 \
        _Pragma("unroll")                                                       \
        for (int nf = 0; nf < 4; ++nf) {                                        \
            f16x8 bf = *(const f16x8*)(w1f + (size_t)((tg*4+nf)*64+lane)*8);    \
            acc[nf] = __builtin_amdgcn_mfma_f32_16x16x32_f16(af, bf, acc[nf], 0, 0, 0); \
        }                                                                       \
    }

#pragma unroll
    for (int it = 0; it < 4; ++it) {
        int rg = w * 16 + it * 4 + g;
        f16x4 hv;
        hv[0] = (_Float16)ea4[it].x; hv[1] = (_Float16)ea4[it].y;
        hv[2] = (_Float16)ea4[it].z; hv[3] = (_Float16)ea4[it].w;
        *(f16x4*)&sA[rg][col * 4] = hv;
    }
    MFMA_L1(0)
#pragma unroll
    for (int it = 0; it < 4; ++it) {
        int rg = w * 16 + it * 4 + g;
        f16x4 hv;
        hv[0] = (_Float16)sx4[it].x; hv[1] = (_Float16)sx4[it].y;
        hv[2] = (_Float16)sx4[it].z; hv[3] = (_Float16)sx4[it].w;
        *(f16x4*)&sA[rg][col * 4] = hv;
    }
    MFMA_L1(1)
#pragma unroll
    for (int it = 0; it < 4; ++it) {
        int rg = w * 16 + it * 4 + g;
        f16x4 hv;
        hv[0] = (_Float16)dx4[it].x; hv[1] = (_Float16)dx4[it].y;
        hv[2] = (_Float16)dx4[it].z; hv[3] = (_Float16)dx4[it].w;
        *(f16x4*)&sA[rg][col * 4] = hv;
    }
    MFMA_L1(2)
#undef MFMA_L1

#pragma unroll
    for (int nf = 0; nf < 4; ++nf)
#pragma unroll
        for (int rg = 0; rg < 4; ++rg) {
            int row = w * 16 + g * 4 + rg;
            sA[row][nf * 16 + col] = (_Float16)silu_f(acc[nf][rg]);
        }

    f32x4 out[4];
#pragma unroll
    for (int nf = 0; nf < 4; ++nf) {
        float bv = b2[nf * 16 + col];
        out[nf] = (f32x4){bv, bv, bv, bv};
    }
#pragma unroll
    for (int tt = 0; tt < 2; ++tt) {
        int k0 = tt * 32 + ko;
        f16x8 af = *(const f16x8*)&sA[arow][k0];
#pragma unroll
        for (int nf = 0; nf < 4; ++nf) {
            f16x8 bf = *(const f16x8*)(w2f + (size_t)((tt * 4 + nf) * 64 + lane) * 8);
            out[nf] = __builtin_amdgcn_mfma_f32_16x16x32_f16(af, bf, out[nf], 0, 0, 0);
        }
    }

    // ---- epilogue: scatter f16 rows into sorted ea_mid[pos] ----
    const int rbase = w * 16 + g * 4;
#pragma unroll
    for (int rg = 0; rg < 4; ++rg) {
        long row = base + rbase + rg;
        if (row < E) {
            int pp = __shfl(p0, g * 4 + rg);
#pragma unroll
            for (int nf = 0; nf < 4; ++nf)
                ea_mid[(long)pp * 64 + nf * 16 + col] = (_Float16)out[nf][rg];
        }
    }
}

// ---------------------------------------------------------------------------
// Layer-2 sorted edge kernel: sequential f16 ea_mid read, x gathers via pk,
// in-place f16 ea_mid write + final fp32 scatter to ea_out[eid]. No atomics.
// ---------------------------------------------------------------------------
__global__ __launch_bounds__(256, 8) void gnn_edge_l2(
    const float* __restrict__ x,
    _Float16* __restrict__ ea_mid,
    float* __restrict__ ea_out,
    const int4* __restrict__ pk,
    const _Float16* __restrict__ w1f, const float* __restrict__ b1,
    const _Float16* __restrict__ w2f, const float* __restrict__ b2,
    int E, int nwg)
{
    __shared__ __align__(16) _Float16 sA[64][PWS];

    const int t    = threadIdx.x;
    const int lane = t & 63;
    const int w    = t >> 6;
    const int col  = lane & 15;
    const int g    = lane >> 4;
    const int ko   = g * 8;
    const int bid  = xcd_swz(blockIdx.x, nwg);
    const long base = (long)bid * 64;

    long p0 = base + w * 16 + col;
    if (p0 >= E) p0 = E - 1;
    const int ei0 = pk[p0].x;

    f16x4  ea16v[4];
    float4 sx4[4], dx4[4];
#pragma unroll
    for (int it = 0; it < 4; ++it) {
        long p = base + w * 16 + it * 4 + g;
        if (p >= E) p = E - 1;
        int4 rec = pk[p];
        ea16v[it] = *(const f16x4*)(ea_mid + p * 64 + col * 4);
        sx4[it] = *(const float4*)(x + (long)rec.y * 64 + col * 4);
        dx4[it] = *(const float4*)(x + (long)rec.z * 64 + col * 4);
    }

    f32x4 acc[4];
#pragma unroll
    for (int nf = 0; nf < 4; ++nf) {
        float bv = b1[nf * 16 + col];
        acc[nf] = (f32x4){bv, bv, bv, bv};
    }
    const int arow = w * 16 + col;

#define MFMA_L1(s3)                                                             \
    _Pragma("unroll")                                                           \
    for (int tt = 0; tt < 2; ++tt) {                                            \
        int k0 = tt * 32 + ko;                                                  \
        f16x8 af = *(const f16x8*)&sA[arow][k0];                                \
        int tg = (s3) * 2 + tt;                                                 \
        _Pragma("unroll")                                                       \
        for (int nf = 0; nf < 4; ++nf) {                                        \
            f16x8 bf = *(const f16x8*)(w1f + (size_t)((tg*4+nf)*64+lane)*8);    \
            acc[nf] = __builtin_amdgcn_mfma_f32_16x16x32_f16(af, bf, acc[nf], 0, 0, 0); \
        }                                                                       \
    }

#pragma unroll
    for (int it = 0; it < 4; ++it) {
        int rg = w * 16 + it * 4 + g;
        *(f16x4*)&sA[rg][col * 4] = ea16v[it];
    }
    MFMA_L1(0)
#pragma unroll
    for (int it = 0; it < 4; ++it) {
        int rg = w * 16 + it * 4 + g;
        f16x4 hv;
        hv[0] = (_Float16)sx4[it].x; hv[1] = (_Float16)sx4[it].y;
        hv[2] = (_Float16)sx4[it].z; hv[3] = (_Float16)sx4[it].w;
        *(f16x4*)&sA[rg][col * 4] = hv;
    }
    MFMA_L1(1)
#pragma unroll
    for (int it = 0; it < 4; ++it) {
        int rg = w * 16 + it * 4 + g;
        f16x4 hv;
        hv[0] = (_Float16)dx4[it].x; hv[1] = (_Float16)dx4[it].y;
        hv[2] = (_Float16)dx4[it].z; hv[3] = (_Float16)dx4[it].w;
        *(f16x4*)&sA[rg][col * 4] = hv;
    }
    MFMA_L1(2)
#undef MFMA_L1

#pragma unroll
    for (int nf = 0; nf < 4; ++nf)
#pragma unroll
        for (int rg = 0; rg < 4; ++rg) {
            int row = w * 16 + g * 4 + rg;
            sA[row][nf * 16 + col] = (_Float16)silu_f(acc[nf][rg]);
        }

    f32x4 out[4];
#pragma unroll
    for (int nf = 0; nf < 4; ++nf) {
        float bv = b2[nf * 16 + col];
        out[nf] = (f32x4){bv, bv, bv, bv};
    }
#pragma unroll
    for (int tt = 0; tt < 2; ++tt) {
        int k0 = tt * 32 + ko;
        f16x8 af = *(const f16x8*)&sA[arow][k0];
#pragma unroll
        for (int nf = 0; nf < 4; ++nf) {
            f16x8 bf = *(const f16x8*)(w2f + (size_t)((tt * 4 + nf) * 64 + lane) * 8);
            out[nf] = __builtin_amdgcn_mfma_f32_16x16x32_f16(af, bf, out[nf], 0, 0, 0);
        }
    }

    const int rbase = w * 16 + g * 4;
#pragma unroll
    for (int rg = 0; rg < 4; ++rg) {
        long p = base + rbase + rg;
        if (p < E) {
#pragma unroll
            for (int nf = 0; nf < 4; ++nf)
                ea_mid[p * 64 + nf * 16 + col] = (_Float16)out[nf][rg];
            int eid = __shfl(ei0, g * 4 + rg);
            float* op = ea_out + (long)eid * 64;
#pragma unroll
            for (int nf = 0; nf < 4; ++nf)
                op[nf * 16 + col] = out[nf][rg];
        }
    }
}

// ---------------------------------------------------------------------------
// Fused node kernel: per-lane segment-sum of sorted f16 ea_mid (2-way
// unrolled) feeds the agg half of the MFMA A-fragment directly.
// ---------------------------------------------------------------------------
__global__ __launch_bounds__(256, 4) void gnn_node_fused(
    const float* __restrict__ x_in,
    const _Float16* __restrict__ eaH,
    const int* __restrict__ row_ptr,
    float* __restrict__ x_out,
    const _Float16* __restrict__ w1f, const float* __restrict__ b1,
    const _Float16* __restrict__ w2f, const float* __restrict__ b2,
    int N, int nwg)
{
    __shared__ __align__(16) _Float16 sA[64][PWS];

    const int t    = threadIdx.x;
    const int lane = t & 63;
    const int w    = t >> 6;
    const int col  = lane & 15;
    const int g    = lane >> 4;
    const int ko   = g * 8;
    const int bid  = xcd_swz(blockIdx.x, nwg);
    const long base = (long)bid * 64;

    long nr = base + w * 16 + col;
    if (nr >= N) nr = N - 1;
    const float* px = x_in + nr * 64 + ko;

    float4 v0 = *(const float4*)(px);
    float4 v1 = *(const float4*)(px + 4);
    float4 v2 = *(const float4*)(px + 32);
    float4 v3 = *(const float4*)(px + 36);

    // ---- segment-sum of eaH over this node's sorted range (2-way unroll) ----
    int pe0 = row_ptr[nr], pe1 = row_ptr[nr + 1];
    float s0[8], s1[8];
#pragma unroll
    for (int j = 0; j < 8; ++j) { s0[j] = 0.f; s1[j] = 0.f; }
    int p = pe0;
    for (; p + 2 <= pe1; p += 2) {
        f16x8 a0 = *(const f16x8*)(eaH + (long)p * 64 + ko);
        f16x8 b0 = *(const f16x8*)(eaH + (long)p * 64 + 32 + ko);
        f16x8 a1 = *(const f16x8*)(eaH + (long)(p + 1) * 64 + ko);
        f16x8 b1v = *(const f16x8*)(eaH + (long)(p + 1) * 64 + 32 + ko);
#pragma unroll
        for (int j = 0; j < 8; ++j) {
            s0[j] += (float)a0[j] + (float)a1[j];
            s1[j] += (float)b0[j] + (float)b1v[j];
        }
    }
    if (p < pe1) {
        f16x8 a0 = *(const f16x8*)(eaH + (long)p * 64 + ko);
        f16x8 b0 = *(const f16x8*)(eaH + (long)p * 64 + 32 + ko);
#pragma unroll
        for (int j = 0; j < 8; ++j) { s0[j] += (float)a0[j]; s1[j] += (float)b0[j]; }
    }

    f32x4 acc[4];
#pragma unroll
    for (int nf = 0; nf < 4; ++nf) {
        float bv = b1[nf * 16 + col];
        acc[nf] = (f32x4){bv, bv, bv, bv};
    }

#define QTRV(m, A, B)                                                           \
    {                                                                           \
        f16x8 af;                                                               \
        af[0] = (_Float16)A.x; af[1] = (_Float16)A.y;                           \
        af[2] = (_Float16)A.z; af[3] = (_Float16)A.w;                           \
        af[4] = (_Float16)B.x; af[5] = (_Float16)B.y;                           \
        af[6] = (_Float16)B.z; af[7] = (_Float16)B.w;                           \
        _Pragma("unroll")                                                       \
        for (int nf = 0; nf < 4; ++nf) {                                        \
            f16x8 bf = *(const f16x8*)(w1f + (size_t)(((m)*4+nf)*64+lane)*8);   \
            acc[nf] = __builtin_amdgcn_mfma_f32_16x16x32_f16(af, bf, acc[nf], 0, 0, 0); \
        }                                                                       \
    }
#define QTRS(m, S)                                                              \
    {                                                                           \
        f16x8 af;                                                               \
        _Pragma("unroll")                                                       \
        for (int j = 0; j < 8; ++j) af[j] = (_Float16)S[j];                     \
        _Pragma("unroll")                                                       \
        for (int nf = 0; nf < 4; ++nf) {                                        \
            f16x8 bf = *(const f16x8*)(w1f + (size_t)(((m)*4+nf)*64+lane)*8);   \
            acc[nf] = __builtin_amdgcn_mfma_f32_16x16x32_f16(af, bf, acc[nf], 0, 0, 0); \
        }                                                                       \
    }
    QTRV(0, v0, v1)  QTRV(1, v2, v3)   // x    (k 0..63)
    QTRS(2, s0)      QTRS(3, s1)       // agg  (k 64..127)
#undef QTRV
#undef QTRS

#pragma unroll
    for (int nf = 0; nf < 4; ++nf)
#pragma unroll
        for (int rg = 0; rg < 4; ++rg) {
            int row = w * 16 + g * 4 + rg;
            sA[row][nf * 16 + col] = (_Float16)silu_f(acc[nf][rg]);
        }

    f32x4 out[4];
#pragma unroll
    for (int nf = 0; nf < 4; ++nf) {
        float bv = b2[nf * 16 + col];
        out[nf] = (f32x4){bv, bv, bv, bv};
    }
    const int arow = w * 16 + col;
#pragma unroll
    for (int tt = 0; tt < 2; ++tt) {
        int k0 = tt * 32 + ko;
        f16x8 af = *(const f16x8*)&sA[arow][k0];
#pragma unroll
        for (int nf = 0; nf < 4; ++nf) {
            f16x8 bf = *(const f16x8*)(w2f + (size_t)((tt * 4 + nf) * 64 + lane) * 8);
            out[nf] = __builtin_amdgcn_mfma_f32_16x16x32_f16(af, bf, out[nf], 0, 0, 0);
        }
    }

    const int rbase = w * 16 + g * 4;
#pragma unroll
    for (int rg = 0; rg < 4; ++rg) {
        long row = base + rbase + rg;
        if (row < N) {
            float* op = x_out + row * 64;
#pragma unroll
            for (int nf = 0; nf < 4; ++nf)
                op[nf * 16 + col] = out[nf][rg];
        }
    }
}

// ---------------------------------------------------------------------------
// Fallback unsorted edge kernel (atomics) + plain node kernel — only if
// workspace too small for the sorted pipeline.
// ---------------------------------------------------------------------------
__global__ __launch_bounds__(256, 8) void gnn_edge_mfma(
    const float* __restrict__ x,
    const float* __restrict__ ea_in,
    float* __restrict__ ea_out,
    const int* __restrict__ src_idx,
    const int* __restrict__ dst_idx,
    const _Float16* __restrict__ w1f, const float* __restrict__ b1,
    const _Float16* __restrict__ w2f, const float* __restrict__ b2,
    float* __restrict__ agg, int E)
{
    __shared__ __align__(16) _Float16 sA[64][PWS];

    const int t    = threadIdx.x;
    const int lane = t & 63;
    const int w    = t >> 6;
    const int col  = lane & 15;
    const int g    = lane >> 4;
    const int ko   = g * 8;
    const long base = (long)blockIdx.x * 64;

    long er0 = base + w * 16 + col;
    if (er0 >= E) er0 = E - 1;
    const int di = dst_idx[er0];

    float4 ea4[4], sx4[4], dx4[4];
#pragma unroll
    for (int it = 0; it < 4; ++it) {
        long er = base + w * 16 + it * 4 + g;
        if (er >= E) er = E - 1;
        ea4[it] = *(const float4*)(ea_in + er * 64 + col * 4);
        sx4[it] = *(const float4*)(x + (long)src_idx[er] * 64 + col * 4);
        dx4[it] = *(const float4*)(x + (long)dst_idx[er] * 64 + col * 4);
    }

    f32x4 acc[4];
#pragma unroll
    for (int nf = 0; nf < 4; ++nf) {
        float bv = b1[nf * 16 + col];
        acc[nf] = (f32x4){bv, bv, bv, bv};
    }
    const int arow = w * 16 + col;

#define MFMA_L1(s3)                                                             \
    _Pragma("unroll")                                                           \
    for (int tt = 0; tt < 2; ++tt) {                                            \
        int k0 = tt * 32 + ko;                                                  \
        f16x8 af = *(const f16x8*)&sA[arow][k0];                                \
        int tg = (s3) * 2 + tt;                                                 \
        _Pragma("unroll")                                                       \
        for (int nf = 0; nf < 4; ++nf) {                                        \
            f16x8 bf = *(const f16x8*)(w1f + (size_t)((tg*4+nf)*64+lane)*8);    \
            acc[nf] = __builtin_amdgcn_mfma_f32_16x16x32_f16(af, bf, acc[nf], 0, 0, 0); \
        }                                                                       \
    }

#pragma unroll
    for (int it = 0; it < 4; ++it) {
        int rg = w * 16 + it * 4 + g;
        f16x4 hv;
        hv[0] = (_Float16)ea4[it].x; hv[1] = (_Float16)ea4[it].y;
        hv[2] = (_Float16)ea4[it].z; hv[3] = (_Float16)ea4[it].w;
        *(f16x4*)&sA[rg][col * 4] = hv;
    }
    MFMA_L1(0)
#pragma unroll
    for (int it = 0; it < 4; ++it) {
        int rg = w * 16 + it * 4 + g;
        f16x4 hv;
        hv[0] = (_Float16)sx4[it].x; hv[1] = (_Float16)sx4[it].y;
        hv[2] = (_Float16)sx4[it].z; hv[3] = (_Float16)sx4[it].w;
        *(f16x4*)&sA[rg][col * 4] = hv;
    }
    MFMA_L1(1)
#pragma unroll
    for (int it = 0; it < 4; ++it) {
        int rg = w * 16 + it * 4 + g;
        f16x4 hv;
        hv[0] = (_Float16)dx4[it].x; hv[1] = (_Float16)dx4[it].y;
        hv[2] = (_Float16)dx4[it].z; hv[3] = (_Float16)dx4[it].w;
        *(f16x4*)&sA[rg][col * 4] = hv;
    }
    MFMA_L1(2)
#undef MFMA_L1

#pragma unroll
    for (int nf = 0; nf < 4; ++nf)
#pragma unroll
        for (int rg = 0; rg < 4; ++rg) {
            int row = w * 16 + g * 4 + rg;
            sA[row][nf * 16 + col] = (_Float16)silu_f(acc[nf][rg]);
        }

    f32x4 out[4];
#pragma unroll
    for (int nf = 0; nf < 4; ++nf) {
        float bv = b2[nf * 16 + col];
        out[nf] = (f32x4){bv, bv, bv, bv};
    }
#pragma unroll
    for (int tt = 0; tt < 2; ++tt) {
        int k0 = tt * 32 + ko;
        f16x8 af = *(const f16x8*)&sA[arow][k0];
#pragma unroll
        for (int nf = 0; nf < 4; ++nf) {
            f16x8 bf = *(const f16x8*)(w2f + (size_t)((tt * 4 + nf) * 64 + lane) * 8);
            out[nf] = __builtin_amdgcn_mfma_f32_16x16x32_f16(af, bf, out[nf], 0, 0, 0);
        }
    }

    const int rbase = w * 16 + g * 4;
#pragma unroll
    for (int rg = 0; rg < 4; ++rg) {
        long row = base + rbase + rg;
        if (row < E) {
            int drow = __shfl(di, g * 4 + rg);
            float* ap = agg + (long)drow * 64;
#pragma unroll
            for (int nf = 0; nf < 4; ++nf) {
                ea_out[row * 64 + nf * 16 + col] = out[nf][rg];
                atomicAdd(&ap[nf * 16 + col], out[nf][rg]);
            }
        }
    }
}

__global__ __launch_bounds__(256, 8) void gnn_node_mfma(
    const float* __restrict__ x_in,
    const float* __restrict__ aggp,
    float* __restrict__ x_out,
    const _Float16* __restrict__ w1f, const float* __restrict__ b1,
    const _Float16* __restrict__ w2f, const float* __restrict__ b2, int N)
{
    __shared__ __align__(16) _Float16 sA[64][PWS];

    const int t    = threadIdx.x;
    const int lane = t & 63;
    const int w    = t >> 6;
    const int col  = lane & 15;
    const int g    = lane >> 4;
    const int ko   = g * 8;
    const long base = (long)blockIdx.x * 64;

    long nr = base + w * 16 + col;
    if (nr >= N) nr = N - 1;
    const float* px = x_in + nr * 64 + ko;
    const float* pa = aggp + nr * 64 + ko;

    float4 v0 = *(const float4*)(px);
    float4 v1 = *(const float4*)(px + 4);
    float4 v2 = *(const float4*)(px + 32);
    float4 v3 = *(const float4*)(px + 36);
    float4 v4 = *(const float4*)(pa);
    float4 v5 = *(const float4*)(pa + 4);
    float4 v6 = *(const float4*)(pa + 32);
    float4 v7 = *(const float4*)(pa + 36);

    f32x4 acc[4];
#pragma unroll
    for (int nf = 0; nf < 4; ++nf) {
        float bv = b1[nf * 16 + col];
        acc[nf] = (f32x4){bv, bv, bv, bv};
    }

#define QTR(m, A, B)                                                            \
    {                                                                           \
        f16x8 af;                                                               \
        af[0] = (_Float16)A.x; af[1] = (_Float16)A.y;                           \
        af[2] = (_Float16)A.z; af[3] = (_Float16)A.w;                           \
        af[4] = (_Float16)B.x; af[5] = (_Float16)B.y;                           \
        af[6] = (_Float16)B.z; af[7] = (_Float16)B.w;                           \
        _Pragma("unroll")                                                       \
        for (int nf = 0; nf < 4; ++nf) {                                        \
            f16x8 bf = *(const f16x8*)(w1f + (size_t)(((m)*4+nf)*64+lane)*8);   \
            acc[nf] = __builtin_amdgcn_mfma_f32_16x16x32_f16(af, bf, acc[nf], 0, 0, 0); \
        }                                                                       \
    }
    QTR(0, v0, v1)  QTR(1, v2, v3)
    QTR(2, v4, v5)  QTR(3, v6, v7)
#undef QTR

#pragma unroll
    for (int nf = 0; nf < 4; ++nf)
#pragma unroll
        for (int rg = 0; rg < 4; ++rg) {
            int row = w * 16 + g * 4 + rg;
            sA[row][nf * 16 + col] = (_Float16)silu_f(acc[nf][rg]);
        }

    f32x4 out[4];
#pragma unroll
    for (int nf = 0; nf < 4; ++nf) {
        float bv = b2[nf * 16 + col];
        out[nf] = (f32x4){bv, bv, bv, bv};
    }
    const int arow = w * 16 + col;
#pragma unroll
    for (int tt = 0; tt < 2; ++tt) {
        int k0 = tt * 32 + ko;
        f16x8 af = *(const f16x8*)&sA[arow][k0];
#pragma unroll
        for (int nf = 0; nf < 4; ++nf) {
            f16x8 bf = *(const f16x8*)(w2f + (size_t)((tt * 4 + nf) * 64 + lane) * 8);
            out[nf] = __builtin_amdgcn_mfma_f32_16x16x32_f16(af, bf, out[nf], 0, 0, 0);
        }
    }

    const int rbase = w * 16 + g * 4;
#pragma unroll
    for (int rg = 0; rg < 4; ++rg) {
        long row = base + rbase + rg;
        if (row < N) {
            float* op = x_out + row * 64;
#pragma unroll
            for (int nf = 0; nf < 4; ++nf)
                op[nf * 16 + col] = out[nf][rg];
        }
    }
}

extern "C" void kernel_launch(void* const* d_in, const int* in_sizes, int n_in,
                              void* d_out, int out_size, void* d_ws, size_t ws_size,
                              hipStream_t stream) {
    const int H = 64;
    const int N = in_sizes[0] / H;   // 50000
    const int E = in_sizes[1] / H;   // 800000

    const float* x0  = (const float*)d_in[0];
    const float* ea0 = (const float*)d_in[1];
    const int*   ei  = (const int*)d_in[2];
    const float* ew1 = (const float*)d_in[3];
    const float* eb1 = (const float*)d_in[4];
    const float* ew2 = (const float*)d_in[5];
    const float* eb2 = (const float*)d_in[6];
    const float* nw1 = (const float*)d_in[7];
    const float* nb1 = (const float*)d_in[8];
    const float* nw2 = (const float*)d_in[9];
    const float* nb2 = (const float*)d_in[10];

    float* outX = (float*)d_out;                 // [N, H]
    float* outE = outX + (size_t)N * H;          // [E, H]

    // workspace carve: agg(fallback) | weights | eaH | counts | row_ptr |
    //                  partial | pos | pk
    const size_t aggBytes = (size_t)N * H * sizeof(float);
    const size_t wElems   = 2 * ((size_t)(192 + 64 + 128 + 64) * 64);
    const size_t eaHBytes = (size_t)E * H * sizeof(_Float16);

    float* agg      = (float*)d_ws;
    _Float16* wbase = (_Float16*)((char*)d_ws + aggBytes);
    char* eaH_raw   = (char*)(wbase + wElems);
    eaH_raw = (char*)(((uintptr_t)eaH_raw + 15) & ~(uintptr_t)15);
    _Float16* eaH   = (_Float16*)eaH_raw;
    int* counts     = (int*)(((uintptr_t)((char*)eaH + eaHBytes) + 15) & ~(uintptr_t)15);
    int* row_ptr    = counts + N;
    int* partial    = row_ptr + N + 1;
    int* posA       = partial + 256;
    int4* pk        = (int4*)(((uintptr_t)(posA + E) + 15) & ~(uintptr_t)15);

    const bool sortedOK = ((char*)(pk + E)) <= ((char*)d_ws + ws_size);

    const int* srcI = ei;
    const int* dstI = ei + E;

    WPack pack;
    size_t off = 0;
    _Float16* EW1[2]; _Float16* EW2[2]; _Float16* NW1[2]; _Float16* NW2[2];
    for (int l = 0; l < 2; ++l) {
        EW1[l] = wbase + off; off += 192 * 64;
        EW2[l] = wbase + off; off += 64 * 64;
        NW1[l] = wbase + off; off += 128 * 64;
        NW2[l] = wbase + off; off += 64 * 64;
        pack.d[l * 4 + 0] = {ew1 + (size_t)l * 192 * 64, EW1[l], 192};
        pack.d[l * 4 + 1] = {ew2 + (size_t)l * 64 * 64,  EW2[l], 64};
        pack.d[l * 4 + 2] = {nw1 + (size_t)l * 128 * 64, NW1[l], 128};
        pack.d[l * 4 + 3] = {nw2 + (size_t)l * 64 * 64,  NW2[l], 64};
    }
    conv_weights<<<dim3(48, 8), 256, 0, stream>>>(pack);

    const int egrid = (E + 63) / 64;
    const int ngrid = (N + 63) / 64;
    const int sgrid = (N + 255) / 256;   // scan blocks (196 <= 256)

    if (sortedOK) {
        // ---- CSR build (parallel scan) ----
        (void)hipMemsetAsync(counts, 0, (size_t)N * sizeof(int), stream);
        hist_kernel<<<(E + 255) / 256, 256, 0, stream>>>(dstI, counts, E);
        scan_part<<<sgrid, 256, 0, stream>>>(counts, partial, N);
        scan_mid<<<1, 256, 0, stream>>>(partial, sgrid);
        scan_fin<<<sgrid, 256, 0, stream>>>(counts, partial, row_ptr, N, E);
        scatter_kernel<<<(E + 255) / 256, 256, 0, stream>>>(
            srcI, dstI, counts, pk, posA, E);

        // layer 1: original order, seq ea0 read -> scatter f16 ea_mid[pos]
        gnn_edge_l1<<<egrid, 256, 0, stream>>>(
            x0, ea0, eaH, srcI, dstI, posA,
            EW1[0], eb1, EW2[0], eb2, E, egrid);
        gnn_node_fused<<<ngrid, 256, 0, stream>>>(
            x0, eaH, row_ptr, outX, NW1[0], nb1, NW2[0], nb2, N, ngrid);

        // layer 2: sorted seq read, in-place f16 write + fp32 outE scatter
        gnn_edge_l2<<<egrid, 256, 0, stream>>>(
            outX, eaH, outE, pk,
            EW1[1], eb1 + H, EW2[1], eb2 + H, E, egrid);
        gnn_node_fused<<<ngrid, 256, 0, stream>>>(
            outX, eaH, row_ptr, outX, NW1[1], nb1 + H, NW2[1], nb2 + H, N, ngrid);
    } else {
        // fallback: unsorted path with atomics (R9 structure)
        for (int l = 0; l < 2; ++l) {
            const float* xin  = (l == 0) ? x0  : outX;
            const float* eain = (l == 0) ? ea0 : outE;
            (void)hipMemsetAsync(agg, 0, aggBytes, stream);
            gnn_edge_mfma<<<egrid, 256, 0, stream>>>(
                xin, eain, outE, srcI, dstI,
                EW1[l], eb1 + l * H, EW2[l], eb2 + l * H, agg, E);
            gnn_node_mfma<<<ngrid, 256, 0, stream>>>(
                xin, agg, outX,
                NW1[l], nb1 + l * H, NW2[l], nb2 + l * H, N);
        }
    }
}

// Round 16
// 468.819 us; speedup vs baseline: 1.5170x; 1.0073x over previous
//
#include <hip/hip_runtime.h>

typedef __attribute__((ext_vector_type(8))) _Float16 f16x8;
typedef __attribute__((ext_vector_type(4))) _Float16 f16x4;
typedef __attribute__((ext_vector_type(4))) float f32x4;

#define PWS 72   // LDS tile pitch in halfs: 144B rows, 16B-aligned chunks

__device__ __forceinline__ float silu_f(float v) {
    return v * (1.0f / (1.0f + __expf(-v)));
}

// bijective XCD-aware block swizzle (identity for tiny grids)
__device__ __forceinline__ int xcd_swz(int bid, int nwg) {
    if (nwg < 16) return bid;
    int q = nwg >> 3, r = nwg & 7;
    int x = bid & 7, i = bid >> 3;
    int basex = (x < r) ? x * (q + 1) : r * (q + 1) + (x - r) * q;
    return basex + i;
}

// ---------------------------------------------------------------------------
// Weight pre-conversion: fp32 [K][64] -> f16 in B-fragment order.
// ---------------------------------------------------------------------------
struct WDesc { const float* W; _Float16* out; int K; };
struct WPack { WDesc d[8]; };

__global__ __launch_bounds__(256) void conv_weights(WPack p) {
    WDesc wd = p.d[blockIdx.y];
    int total = wd.K * 64;
    int i = blockIdx.x * 256 + threadIdx.x;
    if (i >= total) return;
    int j  = i & 7;
    int l  = (i >> 3) & 63;
    int tn = i >> 9;                 // t*4 + nf
    int t  = tn >> 2, nf = tn & 3;
    int k  = t * 32 + (l >> 4) * 8 + j;
    int c  = nf * 16 + (l & 15);
    wd.out[i] = (_Float16)wd.W[k * 64 + c];   // RNE
}

// fp32 array -> f16 array (vectorized)
__global__ __launch_bounds__(256) void conv_x(const float* __restrict__ x,
                                              _Float16* __restrict__ xh, int total4) {
    int i = blockIdx.x * 256 + threadIdx.x;
    if (i < total4) {
        float4 v = ((const float4*)x)[i];
        f16x4 h;
        h[0] = (_Float16)v.x; h[1] = (_Float16)v.y;
        h[2] = (_Float16)v.z; h[3] = (_Float16)v.w;
        ((f16x4*)xh)[i] = h;
    }
}

// ---------------------------------------------------------------------------
// CSR build: histogram -> parallel 3-phase scan -> scatter (pk + pos arrays).
// ---------------------------------------------------------------------------
__global__ __launch_bounds__(256) void hist_kernel(const int* __restrict__ dst,
                                                   int* __restrict__ counts, int E) {
    int e = blockIdx.x * 256 + threadIdx.x;
    if (e < E) atomicAdd(&counts[dst[e]], 1);
}

__global__ __launch_bounds__(256) void scan_part(const int* __restrict__ counts,
                                                 int* __restrict__ partial, int N) {
    __shared__ int sm[256];
    int t = threadIdx.x;
    int i = blockIdx.x * 256 + t;
    sm[t] = (i < N) ? counts[i] : 0;
    __syncthreads();
    for (int off = 128; off > 0; off >>= 1) {
        if (t < off) sm[t] += sm[t + off];
        __syncthreads();
    }
    if (t == 0) partial[blockIdx.x] = sm[0];
}

__global__ __launch_bounds__(256) void scan_mid(int* __restrict__ partial, int nP) {
    __shared__ int sm[256];
    int t = threadIdx.x;
    int v = (t < nP) ? partial[t] : 0;
    sm[t] = v;
    __syncthreads();
    for (int off = 1; off < 256; off <<= 1) {
        int add = (t >= off) ? sm[t - off] : 0;
        __syncthreads();
        sm[t] += add;
        __syncthreads();
    }
    if (t < nP) partial[t] = sm[t] - v;      // exclusive base per block
}

__global__ __launch_bounds__(256) void scan_fin(int* __restrict__ counts,
                                                const int* __restrict__ partial,
                                                int* __restrict__ row_ptr,
                                                int N, int E) {
    __shared__ int sm[256];
    int t = threadIdx.x;
    int i = blockIdx.x * 256 + t;
    int v = (i < N) ? counts[i] : 0;
    sm[t] = v;
    __syncthreads();
    for (int off = 1; off < 256; off <<= 1) {
        int add = (t >= off) ? sm[t - off] : 0;
        __syncthreads();
        sm[t] += add;
        __syncthreads();
    }
    int excl = sm[t] - v + partial[blockIdx.x];
    if (i < N) { row_ptr[i] = excl; counts[i] = excl; }   // counts becomes cursor
    if (blockIdx.x == 0 && t == 0) row_ptr[N] = E;
}

__global__ __launch_bounds__(256) void scatter_kernel(
    const int* __restrict__ src, const int* __restrict__ dst,
    int* __restrict__ cursor, int4* __restrict__ pk,
    int* __restrict__ posA, int E) {
    int e = blockIdx.x * 256 + threadIdx.x;
    if (e < E) {
        int d = dst[e];
        int pos = atomicAdd(&cursor[d], 1);
        pk[pos] = make_int4(e, src[e], d, 0);
        posA[e] = pos;
    }
}

// ---------------------------------------------------------------------------
// Layer-1 edge kernel, ORIGINAL edge order: sequential ea0 fp32 read, f16 x
// gathers (half the lines of fp32), no atomics. Result scatter-written as f16
// into sorted ea_mid[pos[e]].
// ---------------------------------------------------------------------------
__global__ __launch_bounds__(256, 8) void gnn_edge_l1(
    const _Float16* __restrict__ xh,
    const float* __restrict__ ea_in,
    _Float16* __restrict__ ea_mid,
    const int* __restrict__ src_idx,
    const int* __restrict__ dst_idx,
    const int* __restrict__ posA,
    const _Float16* __restrict__ w1f, const float* __restrict__ b1,
    const _Float16* __restrict__ w2f, const float* __restrict__ b2,
    int E, int nwg)
{
    __shared__ __align__(16) _Float16 sA[64][PWS];

    const int t    = threadIdx.x;
    const int lane = t & 63;
    const int w    = t >> 6;
    const int col  = lane & 15;
    const int g    = lane >> 4;
    const int ko   = g * 8;
    const int bid  = xcd_swz(blockIdx.x, nwg);
    const long base = (long)bid * 64;

    long er0 = base + w * 16 + col;
    if (er0 >= E) er0 = E - 1;
    const int p0 = posA[er0];          // sorted position of this lane's row

    // ---- upfront loads: rows it*4+g, cols col*4..+4 ----
    float4 ea4[4];
    f16x4  sx16[4], dx16[4];
#pragma unroll
    for (int it = 0; it < 4; ++it) {
        long er = base + w * 16 + it * 4 + g;
        if (er >= E) er = E - 1;
        ea4[it]  = *(const float4*)(ea_in + er * 64 + col * 4);
        sx16[it] = *(const f16x4*)(xh + (long)src_idx[er] * 64 + col * 4);
        dx16[it] = *(const f16x4*)(xh + (long)dst_idx[er] * 64 + col * 4);
    }

    f32x4 acc[4];
#pragma unroll
    for (int nf = 0; nf < 4; ++nf) {
        float bv = b1[nf * 16 + col];
        acc[nf] = (f32x4){bv, bv, bv, bv};
    }
    const int arow = w * 16 + col;

#define MFMA_L1(s3)                                                             \
    _Pragma("unroll")                                                           \
    for (int tt = 0; tt < 2; ++tt) {                                            \
        int k0 = tt * 32 + ko;                                                  \
        f16x8 af = *(const f16x8*)&sA[arow][k0];                                \
        int tg = (s3) * 2 + tt;                                                 \
        _Pragma("unroll")                                                       \
        for (int nf = 0; nf < 4; ++nf) {                                        \
            f16x8 bf = *(const f16x8*)(w1f + (size_t)((tg*4+nf)*64+lane)*8);    \
            acc[nf] = __builtin_amdgcn_mfma_f32_16x16x32_f16(af, bf, acc[nf], 0, 0, 0); \
        }                                                                       \
    }

    // ---- segment 0: edge_attr (fp32 -> f16 cvt) ----
#pragma unroll
    for (int it = 0; it < 4; ++it) {
        int rg = w * 16 + it * 4 + g;
        f16x4 hv;
        hv[0] = (_Float16)ea4[it].x; hv[1] = (_Float16)ea4[it].y;
        hv[2] = (_Float16)ea4[it].z; hv[3] = (_Float16)ea4[it].w;
        *(f16x4*)&sA[rg][col * 4] = hv;
    }
    MFMA_L1(0)

    // ---- segment 1: x[src] (already f16) ----
#pragma unroll
    for (int it = 0; it < 4; ++it) {
        int rg = w * 16 + it * 4 + g;
        *(f16x4*)&sA[rg][col * 4] = sx16[it];
    }
    MFMA_L1(1)

    // ---- segment 2: x[dst] ----
#pragma unroll
    for (int it = 0; it < 4; ++it) {
        int rg = w * 16 + it * 4 + g;
        *(f16x4*)&sA[rg][col * 4] = dx16[it];
    }
    MFMA_L1(2)
#undef MFMA_L1

    // ---- silu -> h staged into the wave's own 16 LDS rows ----
#pragma unroll
    for (int nf = 0; nf < 4; ++nf)
#pragma unroll
        for (int rg = 0; rg < 4; ++rg) {
            int row = w * 16 + g * 4 + rg;
            sA[row][nf * 16 + col] = (_Float16)silu_f(acc[nf][rg]);
        }

    // ---- layer-2 GEMM (K=64) ----
    f32x4 out[4];
#pragma unroll
    for (int nf = 0; nf < 4; ++nf) {
        float bv = b2[nf * 16 + col];
        out[nf] = (f32x4){bv, bv, bv, bv};
    }
#pragma unroll
    for (int tt = 0; tt < 2; ++tt) {
        int k0 = tt * 32 + ko;
        f16x8 af = *(const f16x8*)&sA[arow][k0];
#pragma unroll
        for (int nf = 0; nf < 4; ++nf) {
            f16x8 bf = *(const f16x8*)(w2f + (size_t)((tt * 4 + nf) * 64 + lane) * 8);
            out[nf] = __builtin_amdgcn_mfma_f32_16x16x32_f16(af, bf, out[nf], 0, 0, 0);
        }
    }

    // ---- epilogue: scatter f16 rows into sorted ea_mid[pos] ----
    const int rbase = w * 16 + g * 4;
#pragma unroll
    for (int rg = 0; rg < 4; ++rg) {
        long row = base + rbase + rg;
        if (row < E) {
            int pp = __shfl(p0, g * 4 + rg);
#pragma unroll
            for (int nf = 0; nf < 4; ++nf)
                ea_mid[(long)pp * 64 + nf * 16 + col] = (_Float16)out[nf][rg];
        }
    }
}

// ---------------------------------------------------------------------------
// Layer-2 sorted edge kernel: sequential f16 ea_mid read, f16 x gathers via
// pk, in-place f16 ea_mid write + final fp32 scatter to ea_out[eid].
// ---------------------------------------------------------------------------
__global__ __launch_bounds__(256, 8) void gnn_edge_l2(
    const _Float16* __restrict__ xh,
    _Float16* __restrict__ ea_mid,
    float* __restrict__ ea_out,
    const int4* __restrict__ pk,
    const _Float16* __restrict__ w1f, const float* __restrict__ b1,
    const _Float16* __restrict__ w2f, const float* __restrict__ b2,
    int E, int nwg)
{
    __shared__ __align__(16) _Float16 sA[64][PWS];

    const int t    = threadIdx.x;
    const int lane = t & 63;
    const int w    = t >> 6;
    const int col  = lane & 15;
    const int g    = lane >> 4;
    const int ko   = g * 8;
    const int bid  = xcd_swz(blockIdx.x, nwg);
    const long base = (long)bid * 64;

    long p0 = base + w * 16 + col;
    if (p0 >= E) p0 = E - 1;
    const int ei0 = pk[p0].x;

    f16x4 ea16v[4], sx16[4], dx16[4];
#pragma unroll
    for (int it = 0; it < 4; ++it) {
        long p = base + w * 16 + it * 4 + g;
        if (p >= E) p = E - 1;
        int4 rec = pk[p];
        ea16v[it] = *(const f16x4*)(ea_mid + p * 64 + col * 4);
        sx16[it]  = *(const f16x4*)(xh + (long)rec.y * 64 + col * 4);
        dx16[it]  = *(const f16x4*)(xh + (long)rec.z * 64 + col * 4);
    }

    f32x4 acc[4];
#pragma unroll
    for (int nf = 0; nf < 4; ++nf) {
        float bv = b1[nf * 16 + col];
        acc[nf] = (f32x4){bv, bv, bv, bv};
    }
    const int arow = w * 16 + col;

#define MFMA_L1(s3)                                                             \
    _Pragma("unroll")                                                           \
    for (int tt = 0; tt < 2; ++tt) {                                            \
        int k0 = tt * 32 + ko;                                                  \
        f16x8 af = *(const f16x8*)&sA[arow][k0];                                \
        int tg = (s3) * 2 + tt;                                                 \
        _Pragma("unroll")                                                       \
        for (int nf = 0; nf < 4; ++nf) {                                        \
            f16x8 bf = *(const f16x8*)(w1f + (size_t)((tg*4+nf)*64+lane)*8);    \
            acc[nf] = __builtin_amdgcn_mfma_f32_16x16x32_f16(af, bf, acc[nf], 0, 0, 0); \
        }                                                                       \
    }

#pragma unroll
    for (int it = 0; it < 4; ++it) {
        int rg = w * 16 + it * 4 + g;
        *(f16x4*)&sA[rg][col * 4] = ea16v[it];
    }
    MFMA_L1(0)
#pragma unroll
    for (int it = 0; it < 4; ++it) {
        int rg = w * 16 + it * 4 + g;
        *(f16x4*)&sA[rg][col * 4] = sx16[it];
    }
    MFMA_L1(1)
#pragma unroll
    for (int it = 0; it < 4; ++it) {
        int rg = w * 16 + it * 4 + g;
        *(f16x4*)&sA[rg][col * 4] = dx16[it];
    }
    MFMA_L1(2)
#undef MFMA_L1

#pragma unroll
    for (int nf = 0; nf < 4; ++nf)
#pragma unroll
        for (int rg = 0; rg < 4; ++rg) {
            int row = w * 16 + g * 4 + rg;
            sA[row][nf * 16 + col] = (_Float16)silu_f(acc[nf][rg]);
        }

    f32x4 out[4];
#pragma unroll
    for (int nf = 0; nf < 4; ++nf) {
        float bv = b2[nf * 16 + col];
        out[nf] = (f32x4){bv, bv, bv, bv};
    }
#pragma unroll
    for (int tt = 0; tt < 2; ++tt) {
        int k0 = tt * 32 + ko;
        f16x8 af = *(const f16x8*)&sA[arow][k0];
#pragma unroll
        for (int nf = 0; nf < 4; ++nf) {
            f16x8 bf = *(const f16x8*)(w2f + (size_t)((tt * 4 + nf) * 64 + lane) * 8);
            out[nf] = __builtin_amdgcn_mfma_f32_16x16x32_f16(af, bf, out[nf], 0, 0, 0);
        }
    }

    const int rbase = w * 16 + g * 4;
#pragma unroll
    for (int rg = 0; rg < 4; ++rg) {
        long p = base + rbase + rg;
        if (p < E) {
#pragma unroll
            for (int nf = 0; nf < 4; ++nf)
                ea_mid[p * 64 + nf * 16 + col] = (_Float16)out[nf][rg];
            int eid = __shfl(ei0, g * 4 + rg);
            float* op = ea_out + (long)eid * 64;
#pragma unroll
            for (int nf = 0; nf < 4; ++nf)
                op[nf * 16 + col] = out[nf][rg];
        }
    }
}

// ---------------------------------------------------------------------------
// Fused node kernel: x A-frags direct f16x8 loads; per-lane segment-sum of
// sorted f16 ea_mid (2-way unrolled); optional f16 x_out copy for the next
// edge layer's gathers.
// ---------------------------------------------------------------------------
__global__ __launch_bounds__(256, 4) void gnn_node_fused(
    const _Float16* __restrict__ xh_in,
    const _Float16* __restrict__ eaH,
    const int* __restrict__ row_ptr,
    float* __restrict__ x_out,
    _Float16* __restrict__ xh_out,          // may be null
    const _Float16* __restrict__ w1f, const float* __restrict__ b1,
    const _Float16* __restrict__ w2f, const float* __restrict__ b2,
    int N, int nwg)
{
    __shared__ __align__(16) _Float16 sA[64][PWS];

    const int t    = threadIdx.x;
    const int lane = t & 63;
    const int w    = t >> 6;
    const int col  = lane & 15;
    const int g    = lane >> 4;
    const int ko   = g * 8;
    const int bid  = xcd_swz(blockIdx.x, nwg);
    const long base = (long)bid * 64;

    long nr = base + w * 16 + col;
    if (nr >= N) nr = N - 1;

    f16x8 xa0 = *(const f16x8*)(xh_in + nr * 64 + ko);
    f16x8 xa1 = *(const f16x8*)(xh_in + nr * 64 + 32 + ko);

    // ---- segment-sum of eaH over this node's sorted range (2-way unroll) ----
    int pe0 = row_ptr[nr], pe1 = row_ptr[nr + 1];
    float s0[8], s1[8];
#pragma unroll
    for (int j = 0; j < 8; ++j) { s0[j] = 0.f; s1[j] = 0.f; }
    int p = pe0;
    for (; p + 2 <= pe1; p += 2) {
        f16x8 a0 = *(const f16x8*)(eaH + (long)p * 64 + ko);
        f16x8 b0 = *(const f16x8*)(eaH + (long)p * 64 + 32 + ko);
        f16x8 a1 = *(const f16x8*)(eaH + (long)(p + 1) * 64 + ko);
        f16x8 b1v = *(const f16x8*)(eaH + (long)(p + 1) * 64 + 32 + ko);
#pragma unroll
        for (int j = 0; j < 8; ++j) {
            s0[j] += (float)a0[j] + (float)a1[j];
            s1[j] += (float)b0[j] + (float)b1v[j];
        }
    }
    if (p < pe1) {
        f16x8 a0 = *(const f16x8*)(eaH + (long)p * 64 + ko);
        f16x8 b0 = *(const f16x8*)(eaH + (long)p * 64 + 32 + ko);
#pragma unroll
        for (int j = 0; j < 8; ++j) { s0[j] += (float)a0[j]; s1[j] += (float)b0[j]; }
    }

    f32x4 acc[4];
#pragma unroll
    for (int nf = 0; nf < 4; ++nf) {
        float bv = b1[nf * 16 + col];
        acc[nf] = (f32x4){bv, bv, bv, bv};
    }

#define QTRA(m, AF)                                                             \
    {                                                                           \
        _Pragma("unroll")                                                       \
        for (int nf = 0; nf < 4; ++nf) {                                        \
            f16x8 bf = *(const f16x8*)(w1f + (size_t)(((m)*4+nf)*64+lane)*8);   \
            acc[nf] = __builtin_amdgcn_mfma_f32_16x16x32_f16(AF, bf, acc[nf], 0, 0, 0); \
        }                                                                       \
    }
#define QTRS(m, S)                                                              \
    {                                                                           \
        f16x8 af;                                                               \
        _Pragma("unroll")                                                       \
        for (int j = 0; j < 8; ++j) af[j] = (_Float16)S[j];                     \
        QTRA(m, af)                                                             \
    }
    QTRA(0, xa0)  QTRA(1, xa1)   // x    (k 0..63)
    QTRS(2, s0)   QTRS(3, s1)    // agg  (k 64..127)
#undef QTRA
#undef QTRS

#pragma unroll
    for (int nf = 0; nf < 4; ++nf)
#pragma unroll
        for (int rg = 0; rg < 4; ++rg) {
            int row = w * 16 + g * 4 + rg;
            sA[row][nf * 16 + col] = (_Float16)silu_f(acc[nf][rg]);
        }

    f32x4 out[4];
#pragma unroll
    for (int nf = 0; nf < 4; ++nf) {
        float bv = b2[nf * 16 + col];
        out[nf] = (f32x4){bv, bv, bv, bv};
    }
    const int arow = w * 16 + col;
#pragma unroll
    for (int tt = 0; tt < 2; ++tt) {
        int k0 = tt * 32 + ko;
        f16x8 af = *(const f16x8*)&sA[arow][k0];
#pragma unroll
        for (int nf = 0; nf < 4; ++nf) {
            f16x8 bf = *(const f16x8*)(w2f + (size_t)((tt * 4 + nf) * 64 + lane) * 8);
            out[nf] = __builtin_amdgcn_mfma_f32_16x16x32_f16(af, bf, out[nf], 0, 0, 0);
        }
    }

    const int rbase = w * 16 + g * 4;
#pragma unroll
    for (int rg = 0; rg < 4; ++rg) {
        long row = base + rbase + rg;
        if (row < N) {
            float* op = x_out + row * 64;
#pragma unroll
            for (int nf = 0; nf < 4; ++nf)
                op[nf * 16 + col] = out[nf][rg];
            if (xh_out) {
#pragma unroll
                for (int nf = 0; nf < 4; ++nf)
                    xh_out[row * 64 + nf * 16 + col] = (_Float16)out[nf][rg];
            }
        }
    }
}

// ---------------------------------------------------------------------------
// Fallback unsorted edge kernel (atomics) + plain node kernel — only if
// workspace too small for the sorted pipeline.
// ---------------------------------------------------------------------------
__global__ __launch_bounds__(256, 8) void gnn_edge_mfma(
    const float* __restrict__ x,
    const float* __restrict__ ea_in,
    float* __restrict__ ea_out,
    const int* __restrict__ src_idx,
    const int* __restrict__ dst_idx,
    const _Float16* __restrict__ w1f, const float* __restrict__ b1,
    const _Float16* __restrict__ w2f, const float* __restrict__ b2,
    float* __restrict__ agg, int E)
{
    __shared__ __align__(16) _Float16 sA[64][PWS];

    const int t    = threadIdx.x;
    const int lane = t & 63;
    const int w    = t >> 6;
    const int col  = lane & 15;
    const int g    = lane >> 4;
    const int ko   = g * 8;
    const long base = (long)blockIdx.x * 64;

    long er0 = base + w * 16 + col;
    if (er0 >= E) er0 = E - 1;
    const int di = dst_idx[er0];

    float4 ea4[4], sx4[4], dx4[4];
#pragma unroll
    for (int it = 0; it < 4; ++it) {
        long er = base + w * 16 + it * 4 + g;
        if (er >= E) er = E - 1;
        ea4[it] = *(const float4*)(ea_in + er * 64 + col * 4);
        sx4[it] = *(const float4*)(x + (long)src_idx[er] * 64 + col * 4);
        dx4[it] = *(const float4*)(x + (long)dst_idx[er] * 64 + col * 4);
    }

    f32x4 acc[4];
#pragma unroll
    for (int nf = 0; nf < 4; ++nf) {
        float bv = b1[nf * 16 + col];
        acc[nf] = (f32x4){bv, bv, bv, bv};
    }
    const int arow = w * 16 + col;

#define MFMA_L1(s3)                                                             \
    _Pragma("unroll")                                                           \
    for (int tt = 0; tt < 2; ++tt) {                                            \
        int k0 = tt * 32 + ko;                                                  \
        f16x8 af = *(const f16x8*)&sA[arow][k0];                                \
        int tg = (s3) * 2 + tt;                                                 \
        _Pragma("unroll")                                                       \
        for (int nf = 0; nf < 4; ++nf) {                                        \
            f16x8 bf = *(const f16x8*)(w1f + (size_t)((tg*4+nf)*64+lane)*8);    \
            acc[nf] = __builtin_amdgcn_mfma_f32_16x16x32_f16(af, bf, acc[nf], 0, 0, 0); \
        }                                                                       \
    }

#pragma unroll
    for (int it = 0; it < 4; ++it) {
        int rg = w * 16 + it * 4 + g;
        f16x4 hv;
        hv[0] = (_Float16)ea4[it].x; hv[1] = (_Float16)ea4[it].y;
        hv[2] = (_Float16)ea4[it].z; hv[3] = (_Float16)ea4[it].w;
        *(f16x4*)&sA[rg][col * 4] = hv;
    }
    MFMA_L1(0)
#pragma unroll
    for (int it = 0; it < 4; ++it) {
        int rg = w * 16 + it * 4 + g;
        f16x4 hv;
        hv[0] = (_Float16)sx4[it].x; hv[1] = (_Float16)sx4[it].y;
        hv[2] = (_Float16)sx4[it].z; hv[3] = (_Float16)sx4[it].w;
        *(f16x4*)&sA[rg][col * 4] = hv;
    }
    MFMA_L1(1)
#pragma unroll
    for (int it = 0; it < 4; ++it) {
        int rg = w * 16 + it * 4 + g;
        f16x4 hv;
        hv[0] = (_Float16)dx4[it].x; hv[1] = (_Float16)dx4[it].y;
        hv[2] = (_Float16)dx4[it].z; hv[3] = (_Float16)dx4[it].w;
        *(f16x4*)&sA[rg][col * 4] = hv;
    }
    MFMA_L1(2)
#undef MFMA_L1

#pragma unroll
    for (int nf = 0; nf < 4; ++nf)
#pragma unroll
        for (int rg = 0; rg < 4; ++rg) {
            int row = w * 16 + g * 4 + rg;
            sA[row][nf * 16 + col] = (_Float16)silu_f(acc[nf][rg]);
        }

    f32x4 out[4];
#pragma unroll
    for (int nf = 0; nf < 4; ++nf) {
        float bv = b2[nf * 16 + col];
        out[nf] = (f32x4){bv, bv, bv, bv};
    }
#pragma unroll
    for (int tt = 0; tt < 2; ++tt) {
        int k0 = tt * 32 + ko;
        f16x8 af = *(const f16x8*)&sA[arow][k0];
#pragma unroll
        for (int nf = 0; nf < 4; ++nf) {
            f16x8 bf = *(const f16x8*)(w2f + (size_t)((tt * 4 + nf) * 64 + lane) * 8);
            out[nf] = __builtin_amdgcn_mfma_f32_16x16x32_f16(af, bf, out[nf], 0, 0, 0);
        }
    }

    const int rbase = w * 16 + g * 4;
#pragma unroll
    for (int rg = 0; rg < 4; ++rg) {
        long row = base + rbase + rg;
        if (row < E) {
            int drow = __shfl(di, g * 4 + rg);
            float* ap = agg + (long)drow * 64;
#pragma unroll
            for (int nf = 0; nf < 4; ++nf) {
                ea_out[row * 64 + nf * 16 + col] = out[nf][rg];
                atomicAdd(&ap[nf * 16 + col], out[nf][rg]);
            }
        }
    }
}

__global__ __launch_bounds__(256, 8) void gnn_node_mfma(
    const float* __restrict__ x_in,
    const float* __restrict__ aggp,
    float* __restrict__ x_out,
    const _Float16* __restrict__ w1f, const float* __restrict__ b1,
    const _Float16* __restrict__ w2f, const float* __restrict__ b2, int N)
{
    __shared__ __align__(16) _Float16 sA[64][PWS];

    const int t    = threadIdx.x;
    const int lane = t & 63;
    const int w    = t >> 6;
    const int col  = lane & 15;
    const int g    = lane >> 4;
    const int ko   = g * 8;
    const long base = (long)blockIdx.x * 64;

    long nr = base + w * 16 + col;
    if (nr >= N) nr = N - 1;
    const float* px = x_in + nr * 64 + ko;
    const float* pa = aggp + nr * 64 + ko;

    float4 v0 = *(const float4*)(px);
    float4 v1 = *(const float4*)(px + 4);
    float4 v2 = *(const float4*)(px + 32);
    float4 v3 = *(const float4*)(px + 36);
    float4 v4 = *(const float4*)(pa);
    float4 v5 = *(const float4*)(pa + 4);
    float4 v6 = *(const float4*)(pa + 32);
    float4 v7 = *(const float4*)(pa + 36);

    f32x4 acc[4];
#pragma unroll
    for (int nf = 0; nf < 4; ++nf) {
        float bv = b1[nf * 16 + col];
        acc[nf] = (f32x4){bv, bv, bv, bv};
    }

#define QTR(m, A, B)                                                            \
    {                                                                           \
        f16x8 af;                                                               \
        af[0] = (_Float16)A.x; af[1] = (_Float16)A.y;                           \
        af[2] = (_Float16)A.z; af[3] = (_Float16)A.w;                           \
        af[4] = (_Float16)B.x; af[5] = (_Float16)B.y;                           \
        af[6] = (_Float16)B.z; af[7] = (_Float16)B.w;                           \
        _Pragma("unroll")                                                       \
        for (int nf = 0; nf < 4; ++nf) {                                        \
            f16x8 bf = *(const f16x8*)(w1f + (size_t)(((m)*4+nf)*64+lane)*8);   \
            acc[nf] = __builtin_amdgcn_mfma_f32_16x16x32_f16(af, bf, acc[nf], 0, 0, 0); \
        }                                                                       \
    }
    QTR(0, v0, v1)  QTR(1, v2, v3)
    QTR(2, v4, v5)  QTR(3, v6, v7)
#undef QTR

#pragma unroll
    for (int nf = 0; nf < 4; ++nf)
#pragma unroll
        for (int rg = 0; rg < 4; ++rg) {
            int row = w * 16 + g * 4 + rg;
            sA[row][nf * 16 + col] = (_Float16)silu_f(acc[nf][rg]);
        }

    f32x4 out[4];
#pragma unroll
    for (int nf = 0; nf < 4; ++nf) {
        float bv = b2[nf * 16 + col];
        out[nf] = (f32x4){bv, bv, bv, bv};
    }
    const int arow = w * 16 + col;
#pragma unroll
    for (int tt = 0; tt < 2; ++tt) {
        int k0 = tt * 32 + ko;
        f16x8 af = *(const f16x8*)&sA[arow][k0];
#pragma unroll
        for (int nf = 0; nf < 4; ++nf) {
            f16x8 bf = *(const f16x8*)(w2f + (size_t)((tt * 4 + nf) * 64 + lane) * 8);
            out[nf] = __builtin_amdgcn_mfma_f32_16x16x32_f16(af, bf, out[nf], 0, 0, 0);
        }
    }

    const int rbase = w * 16 + g * 4;
#pragma unroll
    for (int rg = 0; rg < 4; ++rg) {
        long row = base + rbase + rg;
        if (row < N) {
            float* op = x_out + row * 64;
#pragma unroll
            for (int nf = 0; nf < 4; ++nf)
                op[nf * 16 + col] = out[nf][rg];
        }
    }
}

extern "C" void kernel_launch(void* const* d_in, const int* in_sizes, int n_in,
                              void* d_out, int out_size, void* d_ws, size_t ws_size,
                              hipStream_t stream) {
    const int H = 64;
    const int N = in_sizes[0] / H;   // 50000
    const int E = in_sizes[1] / H;   // 800000

    const float* x0  = (const float*)d_in[0];
    const float* ea0 = (const float*)d_in[1];
    const int*   ei  = (const int*)d_in[2];
    const float* ew1 = (const float*)d_in[3];
    const float* eb1 = (const float*)d_in[4];
    const float* ew2 = (const float*)d_in[5];
    const float* eb2 = (const float*)d_in[6];
    const float* nw1 = (const float*)d_in[7];
    const float* nb1 = (const float*)d_in[8];
    const float* nw2 = (const float*)d_in[9];
    const float* nb2 = (const float*)d_in[10];

    float* outX = (float*)d_out;                 // [N, H]
    float* outE = outX + (size_t)N * H;          // [E, H]

    // workspace carve: agg(fallback, aliased by xh0/xh1) | weights | eaH |
    //                  counts | row_ptr | partial | pos | pk
    const size_t aggBytes = (size_t)N * H * sizeof(float);
    const size_t wElems   = 2 * ((size_t)(192 + 64 + 128 + 64) * 64);
    const size_t eaHBytes = (size_t)E * H * sizeof(_Float16);

    float* agg      = (float*)d_ws;
    _Float16* xh0   = (_Float16*)d_ws;                   // aliases agg (sorted path only)
    _Float16* xh1   = xh0 + (size_t)N * H;
    _Float16* wbase = (_Float16*)((char*)d_ws + aggBytes);
    char* eaH_raw   = (char*)(wbase + wElems);
    eaH_raw = (char*)(((uintptr_t)eaH_raw + 15) & ~(uintptr_t)15);
    _Float16* eaH   = (_Float16*)eaH_raw;
    int* counts     = (int*)(((uintptr_t)((char*)eaH + eaHBytes) + 15) & ~(uintptr_t)15);
    int* row_ptr    = counts + N;
    int* partial    = row_ptr + N + 1;
    int* posA       = partial + 256;
    int4* pk        = (int4*)(((uintptr_t)(posA + E) + 15) & ~(uintptr_t)15);

    const bool sortedOK = ((char*)(pk + E)) <= ((char*)d_ws + ws_size);

    const int* srcI = ei;
    const int* dstI = ei + E;

    WPack pack;
    size_t off = 0;
    _Float16* EW1[2]; _Float16* EW2[2]; _Float16* NW1[2]; _Float16* NW2[2];
    for (int l = 0; l < 2; ++l) {
        EW1[l] = wbase + off; off += 192 * 64;
        EW2[l] = wbase + off; off += 64 * 64;
        NW1[l] = wbase + off; off += 128 * 64;
        NW2[l] = wbase + off; off += 64 * 64;
        pack.d[l * 4 + 0] = {ew1 + (size_t)l * 192 * 64, EW1[l], 192};
        pack.d[l * 4 + 1] = {ew2 + (size_t)l * 64 * 64,  EW2[l], 64};
        pack.d[l * 4 + 2] = {nw1 + (size_t)l * 128 * 64, NW1[l], 128};
        pack.d[l * 4 + 3] = {nw2 + (size_t)l * 64 * 64,  NW2[l], 64};
    }
    conv_weights<<<dim3(48, 8), 256, 0, stream>>>(pack);

    const int egrid = (E + 63) / 64;
    const int ngrid = (N + 63) / 64;
    const int sgrid = (N + 255) / 256;   // scan blocks (196 <= 256)

    if (sortedOK) {
        // x0 -> f16 table
        const int x4 = N * H / 4;
        conv_x<<<(x4 + 255) / 256, 256, 0, stream>>>(x0, xh0, x4);

        // ---- CSR build (parallel scan) ----
        (void)hipMemsetAsync(counts, 0, (size_t)N * sizeof(int), stream);
        hist_kernel<<<(E + 255) / 256, 256, 0, stream>>>(dstI, counts, E);
        scan_part<<<sgrid, 256, 0, stream>>>(counts, partial, N);
        scan_mid<<<1, 256, 0, stream>>>(partial, sgrid);
        scan_fin<<<sgrid, 256, 0, stream>>>(counts, partial, row_ptr, N, E);
        scatter_kernel<<<(E + 255) / 256, 256, 0, stream>>>(
            srcI, dstI, counts, pk, posA, E);

        // layer 1: original order, seq ea0 read -> scatter f16 ea_mid[pos]
        gnn_edge_l1<<<egrid, 256, 0, stream>>>(
            xh0, ea0, eaH, srcI, dstI, posA,
            EW1[0], eb1, EW2[0], eb2, E, egrid);
        gnn_node_fused<<<ngrid, 256, 0, stream>>>(
            xh0, eaH, row_ptr, outX, xh1, NW1[0], nb1, NW2[0], nb2, N, ngrid);

        // layer 2: sorted seq read, in-place f16 write + fp32 outE scatter
        gnn_edge_l2<<<egrid, 256, 0, stream>>>(
            xh1, eaH, outE, pk,
            EW1[1], eb1 + H, EW2[1], eb2 + H, E, egrid);
        gnn_node_fused<<<ngrid, 256, 0, stream>>>(
            xh1, eaH, row_ptr, outX, nullptr, NW1[1], nb1 + H, NW2[1], nb2 + H, N, ngrid);
    } else {
        // fallback: unsorted path with atomics (R9 structure)
        for (int l = 0; l < 2; ++l) {
            const float* xin  = (l == 0) ? x0  : outX;
            const float* eain = (l == 0) ? ea0 : outE;
            (void)hipMemsetAsync(agg, 0, aggBytes, stream);
            gnn_edge_mfma<<<egrid, 256, 0, stream>>>(
                xin, eain, outE, srcI, dstI,
                EW1[l], eb1 + l * H, EW2[l], eb2 + l * H, agg, E);
            gnn_node_mfma<<<ngrid, 256, 0, stream>>>(
                xin, agg, outX,
                NW1[l], nb1 + l * H, NW2[l], nb2 + l * H, N);
        }
    }
}